// Round 6
// baseline (137.489 us; speedup 1.0000x reference)
//
#include <hip/hip_runtime.h>
#include <hip/hip_bf16.h>
#include <stdint.h>

#define BN_EPS 1e-3f

typedef __bf16 bf16x8 __attribute__((ext_vector_type(8)));
typedef float  f32x16 __attribute__((ext_vector_type(16)));

// Dims: B=256, F=64, Df=H=D=256, E=8. Tokens=16384; tile = 128 tokens (2 batch rows).
// Grid 256 = 128 tiles x 2 expert-halves (eh) = exactly 1 WG/CU; eh parity == XCD parity.
// 512 thr = 8 waves = 2 token-halves (mtg) x 4 nb-pairs (wn): wave tile = 64 tok x 64 cols.
// Per ks-step: 2 LDS A-reads + 2 L2 B-loads -> 4 MFMAs (A shared across nb, B across mt).
// LDS: xb 64K + hb 64K + wrts 2K = 130K -> 1 WG/CU; launch_bounds(512,2) -> 256 reg budget, no spill.
// ws: [0,3.0M) pk (route partials overlay, dead before pack) | fold 32KB | wrt 2KB | wb 64KB
static constexpr size_t WS_FOLD_OFF = 24ull * 131072ull;
static constexpr size_t WS_WRT_OFF  = WS_FOLD_OFF + 32768ull;
static constexpr size_t WS_WB_OFF   = WS_WRT_OFF + 2048ull;

// Swizzled LDS addr: frag-row fr (0..31 = k/8), token tok (0..127), 16B units.
#define XADDR(fr, tok) (((fr) << 11) + ((((tok) ^ ((fr) & 31))) << 4))

// ---------------- BN fold ----------------
__global__ __launch_bounds__(256) void fold_kernel(
    const float* __restrict__ b1, const float* __restrict__ g1, const float* __restrict__ be1,
    const float* __restrict__ m1, const float* __restrict__ v1,
    const float* __restrict__ b2, const float* __restrict__ g2, const float* __restrict__ be2,
    const float* __restrict__ m2, const float* __restrict__ v2,
    float* __restrict__ fold) {
  int i = blockIdx.x * 256 + threadIdx.x;
  if (i < 2048) {
    float s1 = g1[i] * rsqrtf(v1[i] + BN_EPS);
    fold[i]        = s1;
    fold[2048 + i] = (b1[i] - m1[i]) * s1 + be1[i];
    float s2 = g2[i] * rsqrtf(v2[i] + BN_EPS);
    fold[4096 + i] = s2;
    fold[6144 + i] = (b2[i] - m2[i]) * s2 + be2[i];
  }
}

// ---------------- Weight pack: fp32 [E][K][N] -> bf16 MFMA-frag order ----------------
__global__ __launch_bounds__(256) void pack_kernel(
    const float* __restrict__ W1, const float* __restrict__ W2, const float* __restrict__ Wo,
    __bf16* __restrict__ pk) {
  __shared__ float sl[16 * 256];
  int bid = blockIdx.x;             // 384 = 24 mats * 16 ks
  int m = bid >> 4, ks = bid & 15;
  int L = m >> 3, e = m & 7;
  const float* Ws = (L == 0 ? W1 : (L == 1 ? W2 : Wo)) + (size_t)e * 65536 + (size_t)ks * 16 * 256;
  int t = threadIdx.x;
#pragma unroll
  for (int it = 0; it < 4; ++it) {
    int el4 = it * 256 + t;
    float4 v = *reinterpret_cast<const float4*>(Ws + (size_t)el4 * 4);
    *reinterpret_cast<float4*>(&sl[el4 * 4]) = v;
  }
  __syncthreads();
#pragma unroll
  for (int it = 0; it < 2; ++it) {
    int task = it * 256 + t;        // nb(8) x lane(64)
    int nb = task >> 6, l = task & 63;
    int colb = nb * 32 + (l & 31);
    int krow = (l >> 5) * 8;
    union { __bf16 h[8]; int4 v; } u;
#pragma unroll
    for (int i = 0; i < 8; ++i) u.h[i] = (__bf16)sl[(krow + i) * 256 + colb];
    size_t off = ((size_t)(m * 8 + nb) * 16 + ks) * 512 + (size_t)l * 8;
    *reinterpret_cast<int4*>(pk + off) = u.v;
  }
}

// ---------------- Routing pass 1: batch-partial sums ----------------
__global__ __launch_bounds__(256) void route1_kernel(
    const float* __restrict__ x, float* __restrict__ part) {
  int f = blockIdx.x, bq = blockIdx.y, t = threadIdx.x;   // 64 x 8 WGs
  const float* xp = x + (size_t)(bq * 32) * 16384 + f * 256 + t;
  float s = 0.f;
#pragma unroll 4
  for (int bi = 0; bi < 32; ++bi) s += xp[(size_t)bi * 16384];
  part[(size_t)(bq * 64 + f) * 256 + t] = s;
}

// ---------------- Routing pass 2: reduce + softmax + wb ----------------
__global__ __launch_bounds__(256) void route2_kernel(
    const float* __restrict__ part, const float* __restrict__ Wr, const float* __restrict__ br,
    const float* __restrict__ bo, float* __restrict__ wrt, float* __restrict__ wb) {
  __shared__ float feat[256];
  __shared__ float lg[8];
  __shared__ float wsm[8];
  int f = blockIdx.x, t = threadIdx.x;
  float a = 0.f;
#pragma unroll
  for (int bq = 0; bq < 8; ++bq) a += part[(size_t)(bq * 64 + f) * 256 + t];
  feat[t] = a * (1.0f / 256.0f);
  __syncthreads();
  if (t < 8) {
    float s = br[t];
    for (int d = 0; d < 256; ++d) s += feat[d] * Wr[d * 8 + t];
    lg[t] = s;
  }
  __syncthreads();
  if (t == 0) {
    float mx = lg[0];
#pragma unroll
    for (int e = 1; e < 8; ++e) mx = fmaxf(mx, lg[e]);
    float ex[8]; float sum = 0.f;
#pragma unroll
    for (int e = 0; e < 8; ++e) { ex[e] = expf(lg[e] - mx); sum += ex[e]; }
    float inv = 1.0f / sum;
#pragma unroll
    for (int e = 0; e < 8; ++e) { float v = ex[e] * inv; wsm[e] = v; wrt[f * 8 + e] = v; }
  }
  __syncthreads();
  float o = 0.f;
#pragma unroll
  for (int e = 0; e < 8; ++e) o += wsm[e] * bo[e * 256 + t];
  wb[f * 256 + t] = o;
}

// ---------------- Main fused MoE ----------------
// SWAP=1 (L0/L1): acc = mfma(Wfrag, actfrag) -> C rows = h-cols, cols = tokens.
// ZERO=0 (L2): accumulate into caller's outacc across experts.
__device__ __forceinline__ void sweep128(
    const char* __restrict__ src, const __bf16* __restrict__ pb,
    int l, int l31, int hi, int mtg, int swap, int zero, f32x16 acc[2][2]) {
  if (zero) {
#pragma unroll
    for (int nbi = 0; nbi < 2; ++nbi)
#pragma unroll
      for (int mt = 0; mt < 2; ++mt)
#pragma unroll
        for (int r = 0; r < 16; ++r) acc[nbi][mt][r] = 0.f;
  }
#pragma unroll
  for (int ks = 0; ks < 16; ++ks) {
    bf16x8 b0 = *reinterpret_cast<const bf16x8*>(pb + (size_t)ks * 512 + (size_t)l * 8);
    bf16x8 b1 = *reinterpret_cast<const bf16x8*>(pb + 8192 + (size_t)ks * 512 + (size_t)l * 8);
    int fr = 2 * ks + hi;
    bf16x8 a0 = *reinterpret_cast<const bf16x8*>(src + XADDR(fr, mtg * 64 + l31));
    bf16x8 a1 = *reinterpret_cast<const bf16x8*>(src + XADDR(fr, mtg * 64 + 32 + l31));
    if (swap) {
      acc[0][0] = __builtin_amdgcn_mfma_f32_32x32x16_bf16(b0, a0, acc[0][0], 0, 0, 0);
      acc[0][1] = __builtin_amdgcn_mfma_f32_32x32x16_bf16(b0, a1, acc[0][1], 0, 0, 0);
      acc[1][0] = __builtin_amdgcn_mfma_f32_32x32x16_bf16(b1, a0, acc[1][0], 0, 0, 0);
      acc[1][1] = __builtin_amdgcn_mfma_f32_32x32x16_bf16(b1, a1, acc[1][1], 0, 0, 0);
    } else {
      acc[0][0] = __builtin_amdgcn_mfma_f32_32x32x16_bf16(a0, b0, acc[0][0], 0, 0, 0);
      acc[0][1] = __builtin_amdgcn_mfma_f32_32x32x16_bf16(a1, b0, acc[0][1], 0, 0, 0);
      acc[1][0] = __builtin_amdgcn_mfma_f32_32x32x16_bf16(a0, b1, acc[1][0], 0, 0, 0);
      acc[1][1] = __builtin_amdgcn_mfma_f32_32x32x16_bf16(a1, b1, acc[1][1], 0, 0, 0);
    }
  }
}

// Epilogue for swapped phases: BN + relu (+ optional per-token wrt scale), pack, LDS store.
__device__ __forceinline__ void epi_store(
    const f32x16 acc[2][2], const float* __restrict__ sA, const float* __restrict__ cA,
    char* __restrict__ dst, int l31, int hi, int mtg, int wn, float w0, float w1) {
#pragma unroll
  for (int nbi = 0; nbi < 2; ++nbi) {
#pragma unroll
    for (int g = 0; g < 4; ++g) {
      float4 s4 = *reinterpret_cast<const float4*>(sA + nbi * 32 + 8 * g);
      float4 c4 = *reinterpret_cast<const float4*>(cA + nbi * 32 + 8 * g);
      int fr = (wn * 2 + nbi) * 4 + g;
#pragma unroll
      for (int mt = 0; mt < 2; ++mt) {
        float wm = (mt == 0) ? w0 : w1;
        union { __bf16 h[4]; uint2 u; } p;
#pragma unroll
        for (int j = 0; j < 4; ++j) {
          float sj = (&s4.x)[j], cj = (&c4.x)[j];
          p.h[j] = (__bf16)(wm * fmaxf(acc[nbi][mt][4 * g + j] * sj + cj, 0.f));
        }
        int tok = mtg * 64 + mt * 32 + l31;
        *reinterpret_cast<uint2*>(dst + XADDR(fr, tok) + hi * 8) = p.u;
      }
    }
  }
}

__global__ __launch_bounds__(512, 2) void moe_kernel(
    const float* __restrict__ x, const __bf16* __restrict__ pk,
    const float* __restrict__ fold, const float* __restrict__ wrt,
    const float* __restrict__ wb, float* __restrict__ out) {
  __shared__ char xb[65536];
  __shared__ char hb[65536];
  __shared__ float wrts[512];
  const int tid = threadIdx.x;
  const int l = tid & 63, w = tid >> 6;
  const int l31 = l & 31, hi = l >> 5;
  const int wn = w & 3, mtg = w >> 2;
  const int bid = blockIdx.x;
  const int tile = bid >> 1, eh = bid & 1;

  // ---- stage x -> bf16 LDS (swizzled; coalesced global reads) ----
  {
    const float* xg = x + (size_t)tile * 32768;
#pragma unroll
    for (int i = 0; i < 8; ++i) {
      int u = i * 512 + tid;           // 4096 16B-units: tok(128) x k8(32)
      int tok = u >> 5, k8 = u & 31;
      const float* src = xg + (size_t)tok * 256 + k8 * 8;
      float4 v0 = *reinterpret_cast<const float4*>(src);
      float4 v1 = *reinterpret_cast<const float4*>(src + 4);
      union { __bf16 h[8]; int4 v; } p;
      p.h[0] = (__bf16)v0.x; p.h[1] = (__bf16)v0.y; p.h[2] = (__bf16)v0.z; p.h[3] = (__bf16)v0.w;
      p.h[4] = (__bf16)v1.x; p.h[5] = (__bf16)v1.y; p.h[6] = (__bf16)v1.z; p.h[7] = (__bf16)v1.w;
      *reinterpret_cast<int4*>(xb + XADDR(k8, tok)) = p.v;
    }
  }
  wrts[tid] = wrt[tid];   // 512 = 64 f x 8 e

  f32x16 outacc[2][2];    // L2 accumulates weighted expert sum directly
#pragma unroll
  for (int nbi = 0; nbi < 2; ++nbi)
#pragma unroll
    for (int mt = 0; mt < 2; ++mt)
#pragma unroll
      for (int r = 0; r < 16; ++r) outacc[nbi][mt][r] = 0.f;

  __syncthreads();

  f32x16 acc[2][2];
#pragma unroll 1
  for (int ep = 0; ep < 4; ++ep) {
    const int e = eh * 4 + ep;
    // L0: read xb -> acc
    sweep128(xb, pk + (size_t)((0 * 8 + e) * 8 + wn * 2) * 8192, l, l31, hi, mtg, 1, 1, acc);
    __syncthreads();   // prev L2 done reading hb
    epi_store(acc, fold + 0 * 4096 + e * 256 + wn * 64 + 4 * hi,
              fold + 0 * 4096 + 2048 + e * 256 + wn * 64 + 4 * hi, hb, l31, hi, mtg, wn, 1.f, 1.f);
    __syncthreads();   // hb visible
    // L1: read hb -> acc (in-place; barrier separates read & write); fold wrt into h
    sweep128(hb, pk + (size_t)((1 * 8 + e) * 8 + wn * 2) * 8192, l, l31, hi, mtg, 1, 1, acc);
    __syncthreads();   // all reads done
    {
      float w0 = wrts[l31 * 8 + e];
      float w1 = wrts[(32 + l31) * 8 + e];
      epi_store(acc, fold + 1 * 4096 + e * 256 + wn * 64 + 4 * hi,
                fold + 1 * 4096 + 2048 + e * 256 + wn * 64 + 4 * hi, hb, l31, hi, mtg, wn, w0, w1);
    }
    __syncthreads();   // hb visible
    // L2 (normal): outacc += (wrt*h) @ Wo  (direct MFMA accumulate, no barrier)
    sweep128(hb, pk + (size_t)((2 * 8 + e) * 8 + wn * 2) * 8192, l, l31, hi, mtg, 0, 0, outacc);
  }

  // ---- combine: 2 commutative fp32 atomics per element (deterministic) ----
  float* og = out + (size_t)tile * 32768;
#pragma unroll
  for (int nbi = 0; nbi < 2; ++nbi) {
    int col = (wn * 2 + nbi) * 32 + l31;
#pragma unroll
    for (int mt = 0; mt < 2; ++mt) {
#pragma unroll
      for (int r = 0; r < 16; ++r) {
        int f = mt * 32 + 4 * hi + (r & 3) + 8 * (r >> 2);   // f-index within 64
        int row = mtg * 64 + f;
        float v = outacc[nbi][mt][r];
        if (eh == 0) v += wb[f * 256 + col];
        unsafeAtomicAdd(og + row * 256 + col, v);
      }
    }
  }
}

extern "C" void kernel_launch(void* const* d_in, const int* in_sizes, int n_in,
                              void* d_out, int out_size, void* d_ws, size_t ws_size,
                              hipStream_t stream) {
  const float* x   = (const float*)d_in[0];
  const float* Wr  = (const float*)d_in[1];
  const float* br  = (const float*)d_in[2];
  const float* W1  = (const float*)d_in[3];
  const float* b1  = (const float*)d_in[4];
  const float* g1  = (const float*)d_in[5];
  const float* be1 = (const float*)d_in[6];
  const float* m1  = (const float*)d_in[7];
  const float* v1  = (const float*)d_in[8];
  const float* W2  = (const float*)d_in[9];
  const float* b2  = (const float*)d_in[10];
  const float* g2  = (const float*)d_in[11];
  const float* be2 = (const float*)d_in[12];
  const float* m2  = (const float*)d_in[13];
  const float* v2  = (const float*)d_in[14];
  const float* Wo  = (const float*)d_in[15];
  const float* bo  = (const float*)d_in[16];
  float* out = (float*)d_out;

  __bf16* pk  = (__bf16*)d_ws;
  float* part = (float*)d_ws;                          // overlays pk; dead before pack
  float* fold = (float*)((char*)d_ws + WS_FOLD_OFF);
  float* wrt  = (float*)((char*)d_ws + WS_WRT_OFF);
  float* wb   = (float*)((char*)d_ws + WS_WB_OFF);

  hipMemsetAsync(out, 0, (size_t)out_size * sizeof(float), stream);
  hipLaunchKernelGGL(route1_kernel, dim3(64, 8), dim3(256), 0, stream, x, part);
  hipLaunchKernelGGL(route2_kernel, dim3(64), dim3(256), 0, stream, part, Wr, br, bo, wrt, wb);
  hipLaunchKernelGGL(fold_kernel, dim3(8), dim3(256), 0, stream,
                     b1, g1, be1, m1, v1, b2, g2, be2, m2, v2, fold);
  hipLaunchKernelGGL(pack_kernel, dim3(384), dim3(256), 0, stream, W1, W2, Wo, pk);
  hipLaunchKernelGGL(moe_kernel, dim3(256), dim3(512), 0, stream, x, pk, fold, wrt, wb, out);
}

// Round 8
// 108.874 us; speedup vs baseline: 1.2628x; 1.2628x over previous
//
#include <hip/hip_runtime.h>
#include <hip/hip_bf16.h>
#include <stdint.h>

#define BN_EPS 1e-3f

typedef __bf16 bf16x8 __attribute__((ext_vector_type(8)));
typedef float  f32x16 __attribute__((ext_vector_type(16)));

#define MFMA __builtin_amdgcn_mfma_f32_32x32x16_bf16

// Dims: B=256, F=64, Df=H=D=256, E=8. tile = 128 tokens (2 batch rows).
// Grid 256 = 128 tiles x 2 expert-halves; eh = bid>>7 so tile's WG pair (bid, bid+128)
// lands on the SAME XCD (128%8==0) -> atomic out lines stay XCD-local.
// 512 thr = 8 waves = 4 wn (col pairs) x 2 mtg (token halves); wave tile 64 tok x 64 cols.
// LDS: xb 64K + hb 64K + wrts 2K = 130K -> 1 WG/CU, 2 waves/SIMD.
// Latency plan: depth-2 register B-prefetch chained ACROSS sweeps; raw s_barrier with
// lgkmcnt-only drain so global loads stay in flight over barriers; A depth-1 prefetch.
static constexpr size_t WS_FOLD_OFF = 24ull * 131072ull;
static constexpr size_t WS_WRT_OFF  = WS_FOLD_OFF + 32768ull;
static constexpr size_t WS_WB_OFF   = WS_WRT_OFF + 2048ull;

// Swizzled LDS addr: frag-row fr (0..31 = k/8), token tok (0..127), 16B units.
#define XADDR(fr, tok) (((fr) << 11) + ((((tok) ^ ((fr) & 31))) << 4))

// LDS-publish barrier: drain ds ops, NOT vmcnt (keep B loads in flight).
#define LBAR() do { \
  asm volatile("s_waitcnt lgkmcnt(0)" ::: "memory"); \
  __builtin_amdgcn_s_barrier(); \
  asm volatile("" ::: "memory"); \
} while (0)

// ---------------- Weight pack (+ BN fold in blocks 0-7) ----------------
__global__ __launch_bounds__(256) void pack_kernel(
    const float* __restrict__ W1, const float* __restrict__ W2, const float* __restrict__ Wo,
    const float* __restrict__ b1, const float* __restrict__ g1, const float* __restrict__ be1,
    const float* __restrict__ m1, const float* __restrict__ v1,
    const float* __restrict__ b2, const float* __restrict__ g2, const float* __restrict__ be2,
    const float* __restrict__ m2, const float* __restrict__ v2,
    __bf16* __restrict__ pk, float* __restrict__ fold) {
  __shared__ float sl[16 * 256];
  int bid = blockIdx.x;             // 384 = 24 mats * 16 ks
  int t = threadIdx.x;
  if (bid < 8) {                    // merged BN fold: i = bid*256 + t in [0,2048)
    int i = bid * 256 + t;
    float s1 = g1[i] * rsqrtf(v1[i] + BN_EPS);
    fold[i]        = s1;
    fold[2048 + i] = (b1[i] - m1[i]) * s1 + be1[i];
    float s2 = g2[i] * rsqrtf(v2[i] + BN_EPS);
    fold[4096 + i] = s2;
    fold[6144 + i] = (b2[i] - m2[i]) * s2 + be2[i];
  }
  int m = bid >> 4, ks = bid & 15;
  int L = m >> 3, e = m & 7;
  const float* Ws = (L == 0 ? W1 : (L == 1 ? W2 : Wo)) + (size_t)e * 65536 + (size_t)ks * 16 * 256;
#pragma unroll
  for (int it = 0; it < 4; ++it) {
    int el4 = it * 256 + t;
    float4 v = *reinterpret_cast<const float4*>(Ws + (size_t)el4 * 4);
    *reinterpret_cast<float4*>(&sl[el4 * 4]) = v;
  }
  __syncthreads();
#pragma unroll
  for (int it = 0; it < 2; ++it) {
    int task = it * 256 + t;        // nb(8) x lane(64)
    int nb = task >> 6, l = task & 63;
    int colb = nb * 32 + (l & 31);
    int krow = (l >> 5) * 8;
    union { __bf16 h[8]; int4 v; } u;
#pragma unroll
    for (int i = 0; i < 8; ++i) u.h[i] = (__bf16)sl[(krow + i) * 256 + colb];
    size_t off = ((size_t)(m * 8 + nb) * 16 + ks) * 512 + (size_t)l * 8;
    *reinterpret_cast<int4*>(pk + off) = u.v;
  }
}

// ---------------- Routing pass 1: zero `out` + batch-partial sums (one BW pass) ----------------
__global__ __launch_bounds__(256) void route1_kernel(
    const float* __restrict__ x, float* __restrict__ part, float* __restrict__ out) {
  int g = blockIdx.x;               // 512 WGs = 64 f x 8 bq
  int f = g & 63, bq = g >> 6;
  int t = threadIdx.x;
  float4 z = {0.f, 0.f, 0.f, 0.f};
  // zero exactly out_size = 4,194,304 floats: 512 WGs x 8192 floats (= 8 x 256 x float4)
  float4* oz = reinterpret_cast<float4*>(out + (size_t)g * 8192);
#pragma unroll
  for (int i = 0; i < 8; ++i) oz[i * 256 + t] = z;
  const float* xp = x + (size_t)(bq * 32) * 16384 + f * 256 + t;
  float s = 0.f;
#pragma unroll 4
  for (int bi = 0; bi < 32; ++bi) s += xp[(size_t)bi * 16384];
  part[(size_t)(bq * 64 + f) * 256 + t] = s;
}

// ---------------- Routing pass 2: reduce + softmax + wb ----------------
__global__ __launch_bounds__(256) void route2_kernel(
    const float* __restrict__ part, const float* __restrict__ Wr, const float* __restrict__ br,
    const float* __restrict__ bo, float* __restrict__ wrt, float* __restrict__ wb) {
  __shared__ float feat[256];
  __shared__ float lg[8];
  __shared__ float wsm[8];
  int f = blockIdx.x, t = threadIdx.x;
  float a = 0.f;
#pragma unroll
  for (int bq = 0; bq < 8; ++bq) a += part[(size_t)(bq * 64 + f) * 256 + t];
  feat[t] = a * (1.0f / 256.0f);
  __syncthreads();
  if (t < 8) {
    float s = br[t];
    for (int d = 0; d < 256; ++d) s += feat[d] * Wr[d * 8 + t];
    lg[t] = s;
  }
  __syncthreads();
  if (t == 0) {
    float mx = lg[0];
#pragma unroll
    for (int e = 1; e < 8; ++e) mx = fmaxf(mx, lg[e]);
    float ex[8]; float sum = 0.f;
#pragma unroll
    for (int e = 0; e < 8; ++e) { ex[e] = expf(lg[e] - mx); sum += ex[e]; }
    float inv = 1.0f / sum;
#pragma unroll
    for (int e = 0; e < 8; ++e) { float v = ex[e] * inv; wsm[e] = v; wrt[f * 8 + e] = v; }
  }
  __syncthreads();
  float o = 0.f;
#pragma unroll
  for (int e = 0; e < 8; ++e) o += wsm[e] * bo[e * 256 + t];
  wb[f * 256 + t] = o;
}

// ---------------- Main fused MoE ----------------
// Sweep with depth-2 B prefetch. On entry (c0,c1) hold pb's ks=0,1 frag-pairs
// (already issued, possibly across the previous barrier). On exit they hold
// pbn's ks=0,1 frag-pairs, issued 1-2 iterations before the sweep ended.
__device__ __forceinline__ void sweep_pf(
    const char* __restrict__ src, const __bf16* __restrict__ pb,
    const __bf16* __restrict__ pbn, int l, int tok0, int hi, int swap, int zero,
    bf16x8& c0x, bf16x8& c0y, bf16x8& c1x, bf16x8& c1y, f32x16 acc[2][2]) {
  if (zero) {
#pragma unroll
    for (int nbi = 0; nbi < 2; ++nbi)
#pragma unroll
      for (int mt = 0; mt < 2; ++mt)
#pragma unroll
        for (int r = 0; r < 16; ++r) acc[nbi][mt][r] = 0.f;
  }
  bf16x8 a0 = *reinterpret_cast<const bf16x8*>(src + XADDR(hi, tok0));
  bf16x8 a1 = *reinterpret_cast<const bf16x8*>(src + XADDR(hi, tok0 + 32));
#pragma unroll
  for (int ks = 0; ks < 16; ++ks) {
    // B prefetch for ks+2 (crosses into pbn at ks=14/15 -> survives the barrier)
    const __bf16* pn = (ks < 14) ? (pb + (size_t)(ks + 2) * 512)
                                 : (pbn + (size_t)(ks - 14) * 512);
    bf16x8 nx = *reinterpret_cast<const bf16x8*>(pn + (size_t)l * 8);
    bf16x8 ny = *reinterpret_cast<const bf16x8*>(pn + 8192 + (size_t)l * 8);
    // A prefetch for ks+1 (wraps harmlessly at ks=15)
    int frn = 2 * ((ks + 1) & 15) + hi;
    bf16x8 an0 = *reinterpret_cast<const bf16x8*>(src + XADDR(frn, tok0));
    bf16x8 an1 = *reinterpret_cast<const bf16x8*>(src + XADDR(frn, tok0 + 32));
    __builtin_amdgcn_s_setprio(1);
    if (swap) {
      acc[0][0] = MFMA(c0x, a0, acc[0][0], 0, 0, 0);
      acc[0][1] = MFMA(c0x, a1, acc[0][1], 0, 0, 0);
      acc[1][0] = MFMA(c0y, a0, acc[1][0], 0, 0, 0);
      acc[1][1] = MFMA(c0y, a1, acc[1][1], 0, 0, 0);
    } else {
      acc[0][0] = MFMA(a0, c0x, acc[0][0], 0, 0, 0);
      acc[0][1] = MFMA(a1, c0x, acc[0][1], 0, 0, 0);
      acc[1][0] = MFMA(a0, c0y, acc[1][0], 0, 0, 0);
      acc[1][1] = MFMA(a1, c0y, acc[1][1], 0, 0, 0);
    }
    __builtin_amdgcn_s_setprio(0);
    c0x = c1x; c0y = c1y; c1x = nx; c1y = ny;
    a0 = an0; a1 = an1;
  }
}

// Epilogue for swapped phases: BN + relu (+ per-token wrt scale), pack bf16, LDS store.
__device__ __forceinline__ void epi_store(
    const f32x16 acc[2][2], const float* __restrict__ sA, const float* __restrict__ cA,
    char* __restrict__ dst, int l31, int hi, int mtg, int wn, float w0, float w1) {
#pragma unroll
  for (int nbi = 0; nbi < 2; ++nbi) {
#pragma unroll
    for (int g = 0; g < 4; ++g) {
      float4 s4 = *reinterpret_cast<const float4*>(sA + nbi * 32 + 8 * g);
      float4 c4 = *reinterpret_cast<const float4*>(cA + nbi * 32 + 8 * g);
      int fr = (wn * 2 + nbi) * 4 + g;
#pragma unroll
      for (int mt = 0; mt < 2; ++mt) {
        float wm = (mt == 0) ? w0 : w1;
        union { __bf16 h[4]; uint2 u; } p;
#pragma unroll
        for (int j = 0; j < 4; ++j) {
          float sj = (&s4.x)[j], cj = (&c4.x)[j];
          p.h[j] = (__bf16)(wm * fmaxf(acc[nbi][mt][4 * g + j] * sj + cj, 0.f));
        }
        int tok = mtg * 64 + mt * 32 + l31;
        *reinterpret_cast<uint2*>(dst + XADDR(fr, tok) + hi * 8) = p.u;
      }
    }
  }
}

__global__ __launch_bounds__(512, 2) void moe_kernel(
    const float* __restrict__ x, const __bf16* __restrict__ pk,
    const float* __restrict__ fold, const float* __restrict__ wrt,
    const float* __restrict__ wb, float* __restrict__ out) {
  __shared__ char xb[65536];
  __shared__ char hb[65536];
  __shared__ float wrts[512];
  const int tid = threadIdx.x;
  const int l = tid & 63, w = tid >> 6;
  const int l31 = l & 31, hi = l >> 5;
  const int wn = w & 3, mtg = w >> 2;
  const int bid = blockIdx.x;
  const int tile = bid & 127, eh = bid >> 7;   // pair (t, t+128) shares an XCD
  const int tok0 = mtg * 64 + l31;

#define PB(L, e) (pk + (size_t)(((L) * 8 + (e)) * 8 + wn * 2) * 8192)

  // ---- B prologue prefetch: in flight while we stage x ----
  const __bf16* pbf = PB(0, eh * 4);
  bf16x8 c0x = *reinterpret_cast<const bf16x8*>(pbf + (size_t)l * 8);
  bf16x8 c0y = *reinterpret_cast<const bf16x8*>(pbf + 8192 + (size_t)l * 8);
  bf16x8 c1x = *reinterpret_cast<const bf16x8*>(pbf + 512 + (size_t)l * 8);
  bf16x8 c1y = *reinterpret_cast<const bf16x8*>(pbf + 8192 + 512 + (size_t)l * 8);

  // ---- stage x -> bf16 LDS (swizzled; coalesced global reads) ----
  {
    const float* xg = x + (size_t)tile * 32768;
#pragma unroll
    for (int i = 0; i < 8; ++i) {
      int u = i * 512 + tid;           // 4096 16B-units: tok(128) x k8(32)
      int tok = u >> 5, k8 = u & 31;
      const float* src = xg + (size_t)tok * 256 + k8 * 8;
      float4 v0 = *reinterpret_cast<const float4*>(src);
      float4 v1 = *reinterpret_cast<const float4*>(src + 4);
      union { __bf16 h[8]; int4 v; } p;
      p.h[0] = (__bf16)v0.x; p.h[1] = (__bf16)v0.y; p.h[2] = (__bf16)v0.z; p.h[3] = (__bf16)v0.w;
      p.h[4] = (__bf16)v1.x; p.h[5] = (__bf16)v1.y; p.h[6] = (__bf16)v1.z; p.h[7] = (__bf16)v1.w;
      *reinterpret_cast<int4*>(xb + XADDR(k8, tok)) = p.v;
    }
  }
  wrts[tid] = wrt[tid];   // 512 = 64 f x 8 e

  f32x16 outacc[2][2];
#pragma unroll
  for (int nbi = 0; nbi < 2; ++nbi)
#pragma unroll
    for (int mt = 0; mt < 2; ++mt)
#pragma unroll
      for (int r = 0; r < 16; ++r) outacc[nbi][mt][r] = 0.f;

  LBAR();   // staging visible

  f32x16 acc[2][2];
#pragma unroll 1
  for (int ep = 0; ep < 4; ++ep) {
    const int e = eh * 4 + ep;
    const __bf16* pb_l0 = PB(0, e);
    const __bf16* pb_l1 = PB(1, e);
    const __bf16* pb_l2 = PB(2, e);
    const __bf16* pb_nx = (ep < 3) ? PB(0, e + 1) : PB(0, eh * 4);
    // L0: read xb -> acc   (B regs chain: c holds pb_l0 ks0/1 on entry)
    sweep_pf(xb, pb_l0, pb_l1, l, tok0, hi, 1, 1, c0x, c0y, c1x, c1y, acc);
    LBAR();   // prev L2 readers of hb are done
    epi_store(acc, fold + 0 * 4096 + e * 256 + wn * 64 + 4 * hi,
              fold + 0 * 4096 + 2048 + e * 256 + wn * 64 + 4 * hi, hb, l31, hi, mtg, wn, 1.f, 1.f);
    LBAR();   // hb visible
    // L1: read hb -> acc (in-place; barriers separate read & write); fold wrt into h
    sweep_pf(hb, pb_l1, pb_l2, l, tok0, hi, 1, 1, c0x, c0y, c1x, c1y, acc);
    LBAR();   // all reads done
    {
      float w0 = wrts[l31 * 8 + e];
      float w1 = wrts[(32 + l31) * 8 + e];
      epi_store(acc, fold + 1 * 4096 + e * 256 + wn * 64 + 4 * hi,
                fold + 1 * 4096 + 2048 + e * 256 + wn * 64 + 4 * hi, hb, l31, hi, mtg, wn, w0, w1);
    }
    LBAR();   // hb visible
    // L2: outacc += (wrt*h) @ Wo  (direct MFMA accumulate, no barrier after)
    sweep_pf(hb, pb_l2, pb_nx, l, tok0, hi, 0, 0, c0x, c0y, c1x, c1y, outacc);
  }
#undef PB

  // ---- combine: 2 commutative fp32 atomics per element (deterministic) ----
  float* og = out + (size_t)tile * 32768;
#pragma unroll
  for (int nbi = 0; nbi < 2; ++nbi) {
    int col = (wn * 2 + nbi) * 32 + l31;
#pragma unroll
    for (int mt = 0; mt < 2; ++mt) {
#pragma unroll
      for (int r = 0; r < 16; ++r) {
        int f = mt * 32 + 4 * hi + (r & 3) + 8 * (r >> 2);   // f-index within 64
        int row = mtg * 64 + f;
        float v = outacc[nbi][mt][r];
        if (eh == 0) v += wb[f * 256 + col];
        unsafeAtomicAdd(og + row * 256 + col, v);
      }
    }
  }
}

extern "C" void kernel_launch(void* const* d_in, const int* in_sizes, int n_in,
                              void* d_out, int out_size, void* d_ws, size_t ws_size,
                              hipStream_t stream) {
  const float* x   = (const float*)d_in[0];
  const float* Wr  = (const float*)d_in[1];
  const float* br  = (const float*)d_in[2];
  const float* W1  = (const float*)d_in[3];
  const float* b1  = (const float*)d_in[4];
  const float* g1  = (const float*)d_in[5];
  const float* be1 = (const float*)d_in[6];
  const float* m1  = (const float*)d_in[7];
  const float* v1  = (const float*)d_in[8];
  const float* W2  = (const float*)d_in[9];
  const float* b2  = (const float*)d_in[10];
  const float* g2  = (const float*)d_in[11];
  const float* be2 = (const float*)d_in[12];
  const float* m2  = (const float*)d_in[13];
  const float* v2  = (const float*)d_in[14];
  const float* Wo  = (const float*)d_in[15];
  const float* bo  = (const float*)d_in[16];
  float* out = (float*)d_out;

  __bf16* pk  = (__bf16*)d_ws;
  float* part = (float*)d_ws;                          // overlays pk; dead before pack
  float* fold = (float*)((char*)d_ws + WS_FOLD_OFF);
  float* wrt  = (float*)((char*)d_ws + WS_WRT_OFF);
  float* wb   = (float*)((char*)d_ws + WS_WB_OFF);

  hipLaunchKernelGGL(route1_kernel, dim3(512), dim3(256), 0, stream, x, part, out);
  hipLaunchKernelGGL(route2_kernel, dim3(64), dim3(256), 0, stream, part, Wr, br, bo, wrt, wb);
  hipLaunchKernelGGL(pack_kernel, dim3(384), dim3(256), 0, stream,
                     W1, W2, Wo, b1, g1, be1, m1, v1, b2, g2, be2, m2, v2, pk, fold);
  hipLaunchKernelGGL(moe_kernel, dim3(256), dim3(512), 0, stream, x, pk, fold, wrt, wb, out);
}